// Round 5
// baseline (109.214 us; speedup 1.0000x reference)
//
#include <hip/hip_runtime.h>

typedef float  f32x4  __attribute__((ext_vector_type(4)));
typedef short  short8 __attribute__((ext_vector_type(8)));
typedef unsigned short ushort_t;
typedef ushort_t us4   __attribute__((ext_vector_type(4)));
typedef ushort_t us8   __attribute__((ext_vector_type(8)));

#define NCOARSE 1024
#define NFINE   4096

__device__ __forceinline__ ushort_t f2bf(float f){
  union { float f; unsigned u; } a; a.f = f;
  unsigned u = a.u;
  return (ushort_t)((u + 0x7fffu + ((u >> 16) & 1u)) >> 16);
}

__device__ __forceinline__ f32x4 splat4(float v){ f32x4 t = {v, v, v, v}; return t; }

// ---- pack fp32 row-major W[K][256] into bf16, MFMA-B-fragment order:
// Wp[(((kc*16+nb)*64 + lane)*8 + j] = W[kc*32 + (lane>>4)*8 + j][nb*16 + (lane&15)]
__global__ void prep_w(const float* __restrict__ W, ushort_t* __restrict__ Wp, int nelem){
  int e = blockIdx.x * 256 + threadIdx.x;
  if (e >= nelem) return;
  int j    = e & 7;
  int lane = (e >> 3) & 63;
  int g    = e >> 9;        // kc*16 + nb
  int nb   = g & 15;
  int kc   = g >> 4;
  int k = kc * 32 + (lane >> 4) * 8 + j;
  int n = nb * 16 + (lane & 15);
  Wp[e] = f2bf(W[k * 256 + n]);
}

// ---- kNN, reference fp32 arithmetic EXACTLY (expansion form, no fma):
//   d2 = max( (sf + sc) - 2*dot, 0 )
// 8 lanes per fine point (128 candidates each), in-register top-3, then
// 3-level shfl_xor merge with lexicographic (d,idx) compare.
__global__ __launch_bounds__(256) void knn_kernel(const float* __restrict__ pos,
                           const float* __restrict__ pos_skip,
                           int* __restrict__ knn_i, float* __restrict__ knn_w){
  __shared__ f32x4 cand[8][129];            // (x,y,z,|c|^2); stride 129 -> disjoint bank quads
  const int tid = threadIdx.x;
  const int b   = blockIdx.x >> 7;          // 128 blocks per cloud (4096/32)
  const int m   = blockIdx.x * 32 + (tid >> 3);
  const int chunk = tid & 7;

  const float* p = pos + (size_t)b * NCOARSE * 3;
  for (int c = tid; c < NCOARSE; c += 256){
    float x = p[3*c], y = p[3*c+1], z = p[3*c+2];
    float sc = __fadd_rn(__fadd_rn(__fmul_rn(x,x), __fmul_rn(y,y)), __fmul_rn(z,z));
    f32x4 v = { x, y, z, sc };
    cand[c >> 7][c & 127] = v;
  }
  __syncthreads();

  const float* q = pos_skip + (size_t)m * 3;
  float qx = q[0], qy = q[1], qz = q[2];
  float sf = __fadd_rn(__fadd_rn(__fmul_rn(qx,qx), __fmul_rn(qy,qy)), __fmul_rn(qz,qz));

  float d0 = 1e30f, d1 = 1e30f, d2 = 1e30f;
  int   i0 = 0,     i1 = 0,     i2 = 0;
  const int gbase = chunk * 128;
  #pragma unroll 4
  for (int i = 0; i < 128; ++i){
    f32x4 v = cand[chunk][i];
    float dot = __fadd_rn(__fadd_rn(__fmul_rn(qx, v.x), __fmul_rn(qy, v.y)),
                          __fmul_rn(qz, v.z));
    float d = __fsub_rn(__fadd_rn(sf, v.w), __fmul_rn(2.0f, dot));
    d = fmaxf(d, 0.0f);
    if (d < d2){
      int gi = gbase + i;
      if (d < d1){
        d2 = d1; i2 = i1;
        if (d < d0){ d1 = d0; i1 = i0; d0 = d; i0 = gi; }
        else       { d1 = d;  i1 = gi; }
      } else { d2 = d; i2 = gi; }
    }
  }

  #pragma unroll
  for (int mlev = 1; mlev <= 4; mlev <<= 1){
    float e0 = __shfl_xor(d0, mlev), e1 = __shfl_xor(d1, mlev), e2 = __shfl_xor(d2, mlev);
    int   j0 = __shfl_xor(i0, mlev), j1 = __shfl_xor(i1, mlev), j2 = __shfl_xor(i2, mlev);
    #pragma unroll
    for (int s = 0; s < 3; ++s){
      float e = (s == 0) ? e0 : (s == 1) ? e1 : e2;
      int   j = (s == 0) ? j0 : (s == 1) ? j1 : j2;
      bool l2 = (e < d2) || (e == d2 && j < i2);
      if (l2){
        bool l1 = (e < d1) || (e == d1 && j < i1);
        if (l1){
          d2 = d1; i2 = i1;
          bool l0 = (e < d0) || (e == d0 && j < i0);
          if (l0){ d1 = d0; i1 = i0; d0 = e; i0 = j; }
          else   { d1 = e;  i1 = j; }
        } else { d2 = e; i2 = j; }
      }
    }
  }

  if (chunk == 0){
    float w0 = 1.0f / fmaxf(d0, 1e-16f);
    float w1 = 1.0f / fmaxf(d1, 1e-16f);
    float w2 = 1.0f / fmaxf(d2, 1e-16f);
    float ws = __fadd_rn(__fadd_rn(w0, w1), w2);
    knn_i[3*m]   = b * NCOARSE + i0;
    knn_i[3*m+1] = b * NCOARSE + i1;
    knn_i[3*m+2] = b * NCOARSE + i2;
    knn_w[3*m]   = w0 / ws;
    knn_w[3*m+1] = w1 / ws;
    knn_w[3*m+2] = w2 / ws;
  }
}

// ---- stage h1 = concat(interp, x_skip) as bf16 [65536][384] in ws.
// Barrier-free, LDS-free, full occupancy: gather latency hidden by TLP.
// 8 threads per fine row; 32 rows per block; 2048 blocks, XCD-swizzled
// (each XCD's blocks touch 2 clouds -> x slices stay in its L2).
__global__ __launch_bounds__(256, 4)
void stage_h1(const float* __restrict__ x, const float* __restrict__ x_skip,
              const int* __restrict__ knn_i, const float* __restrict__ knn_w,
              ushort_t* __restrict__ h1g){
  const int tid = threadIdx.x;
  const int lb  = ((blockIdx.x & 7) << 8) + (blockIdx.x >> 3);  // bijective: 2048 = 8*256
  const int r   = tid >> 3;
  const int sub = tid & 7;
  const int m   = lb * 32 + r;

  int i0 = knn_i[3*m], i1 = knn_i[3*m+1], i2 = knn_i[3*m+2];
  float w0 = knn_w[3*m], w1 = knn_w[3*m+1], w2 = knn_w[3*m+2];
  const f32x4* x0 = (const f32x4*)(x + (size_t)i0 * 256);
  const f32x4* x1 = (const f32x4*)(x + (size_t)i1 * 256);
  const f32x4* x2 = (const f32x4*)(x + (size_t)i2 * 256);
  ushort_t* hrow = h1g + (size_t)m * 384;

  #pragma unroll
  for (int k = 0; k < 4; ++k){
    int c8 = k * 8 + sub;                     // 8-col chunk; 8 subs contiguous 256B
    f32x4 a0 = x0[c8*2], a1 = x0[c8*2+1];
    f32x4 b0 = x1[c8*2], b1 = x1[c8*2+1];
    f32x4 c0 = x2[c8*2], c1 = x2[c8*2+1];
    f32x4 vl = a0 * w0 + b0 * w1 + c0 * w2;
    f32x4 vh = a1 * w0 + b1 * w1 + c1 * w2;
    us8 pk = { f2bf(vl.x), f2bf(vl.y), f2bf(vl.z), f2bf(vl.w),
               f2bf(vh.x), f2bf(vh.y), f2bf(vh.z), f2bf(vh.w) };
    *(us8*)(hrow + c8 * 8) = pk;
  }
  const f32x4* xs = (const f32x4*)(x_skip + (size_t)m * 128);
  #pragma unroll
  for (int k = 0; k < 2; ++k){
    int c8 = k * 8 + sub;
    f32x4 a0 = xs[c8*2], a1 = xs[c8*2+1];
    us8 pk = { f2bf(a0.x), f2bf(a0.y), f2bf(a0.z), f2bf(a0.w),
               f2bf(a1.x), f2bf(a1.y), f2bf(a1.z), f2bf(a1.w) };
    *(us8*)(hrow + 256 + c8 * 8) = pk;
  }
}

// ---- GEMM1(relu) -> GEMM2(relu) from materialized h1 (linear read).
__global__ __launch_bounds__(256, 3)
void gemm_fp(const ushort_t* __restrict__ h1g,
             const ushort_t* __restrict__ W1p, const float* __restrict__ b1,
             const ushort_t* __restrict__ W2p, const float* __restrict__ b2,
             float* __restrict__ out){
  __shared__ ushort_t hbuf[64 * 384];   // 48KB; h1 (swizzled), then h2 overlays
  char* h1b = (char*)hbuf;
  char* h2b = (char*)hbuf;
  const int tid  = threadIdx.x;
  const int lb   = ((blockIdx.x & 7) << 7) + (blockIdx.x >> 3);  // bijective: 1024 = 8*128
  const int row0 = lb * 64;

  // linear coalesced h1-tile read -> swizzled LDS write (one latency exposure)
  {
    const char* src = (const char*)h1g + (size_t)row0 * 768;
    short8 st[12];
    #pragma unroll
    for (int it = 0; it < 12; ++it){
      int gb = it * 4096 + tid * 16;
      st[it] = *(const short8*)(src + gb);
    }
    #pragma unroll
    for (int it = 0; it < 12; ++it){
      int gb  = it * 4096 + tid * 16;
      int row = gb / 768;
      *(short8*)(h1b + (gb ^ ((row & 7) << 4))) = st[it];
    }
  }
  __syncthreads();

  const int wp  = tid >> 6;
  const int lane = tid & 63;
  const int lhi = lane >> 4;
  const int llo = lane & 15;

  // ---- GEMM1: (64x384) @ (384x256), bias in acc init
  f32x4 acc[4][4];
  #pragma unroll
  for (int nbp = 0; nbp < 4; ++nbp){
    float bb = b1[wp * 64 + nbp * 16 + llo];
    #pragma unroll
    for (int mb = 0; mb < 4; ++mb) acc[mb][nbp] = splat4(bb);
  }
  #pragma unroll
  for (int kk = 0; kk < 12; ++kk){
    short8 af[4];
    #pragma unroll
    for (int mb = 0; mb < 4; ++mb){
      int r = mb * 16 + llo;
      int byte = (r * 768 + kk * 64 + lhi * 16) ^ ((r & 7) << 4);
      af[mb] = *(const short8*)(h1b + byte);
    }
    short8 bfr[4];
    #pragma unroll
    for (int nbp = 0; nbp < 4; ++nbp)
      bfr[nbp] = *(const short8*)(W1p + ((size_t)((kk * 16 + wp * 4 + nbp) * 64 + lane)) * 8);
    #pragma unroll
    for (int mb = 0; mb < 4; ++mb)
      #pragma unroll
      for (int nbp = 0; nbp < 4; ++nbp)
        acc[mb][nbp] = __builtin_amdgcn_mfma_f32_16x16x32_bf16(af[mb], bfr[nbp], acc[mb][nbp], 0, 0, 0);
  }
  __syncthreads();   // all h1 reads done before h2 overlays the buffer

  // relu -> bf16 -> h2 (swizzled, overlaying h1)
  #pragma unroll
  for (int mb = 0; mb < 4; ++mb)
    #pragma unroll
    for (int nbp = 0; nbp < 4; ++nbp)
      #pragma unroll
      for (int rg = 0; rg < 4; ++rg){
        int r   = mb * 16 + lhi * 4 + rg;
        int col = wp * 64 + nbp * 16 + llo;
        int byte = (r * 512 + col * 2) ^ ((r & 7) << 4);
        *(ushort_t*)(h2b + byte) = f2bf(fmaxf(acc[mb][nbp][rg], 0.0f));
      }
  __syncthreads();

  // ---- GEMM2: (64x256) @ (256x256)
  f32x4 acc2[4][4];
  #pragma unroll
  for (int nbp = 0; nbp < 4; ++nbp){
    float bb = b2[wp * 64 + nbp * 16 + llo];
    #pragma unroll
    for (int mb = 0; mb < 4; ++mb) acc2[mb][nbp] = splat4(bb);
  }
  #pragma unroll
  for (int kk = 0; kk < 8; ++kk){
    short8 af[4];
    #pragma unroll
    for (int mb = 0; mb < 4; ++mb){
      int r = mb * 16 + llo;
      int byte = (r * 512 + kk * 64 + lhi * 16) ^ ((r & 7) << 4);
      af[mb] = *(const short8*)(h2b + byte);
    }
    short8 bfr[4];
    #pragma unroll
    for (int nbp = 0; nbp < 4; ++nbp)
      bfr[nbp] = *(const short8*)(W2p + ((size_t)((kk * 16 + wp * 4 + nbp) * 64 + lane)) * 8);
    #pragma unroll
    for (int mb = 0; mb < 4; ++mb)
      #pragma unroll
      for (int nbp = 0; nbp < 4; ++nbp)
        acc2[mb][nbp] = __builtin_amdgcn_mfma_f32_16x16x32_bf16(af[mb], bfr[nbp], acc2[mb][nbp], 0, 0, 0);
  }
  // relu -> fp32 out
  #pragma unroll
  for (int mb = 0; mb < 4; ++mb)
    #pragma unroll
    for (int nbp = 0; nbp < 4; ++nbp)
      #pragma unroll
      for (int rg = 0; rg < 4; ++rg){
        int row = row0 + mb * 16 + lhi * 4 + rg;
        int col = wp * 64 + nbp * 16 + llo;
        out[(size_t)row * 256 + col] = fmaxf(acc2[mb][nbp][rg], 0.0f);
      }
}

// ---- FALLBACK (r4 fused kernel) used when ws_size can't hold h1g ----
__global__ __launch_bounds__(256, 3)
void fused_fp(const float* __restrict__ x, const float* __restrict__ x_skip,
              const int* __restrict__ knn_i, const float* __restrict__ knn_w,
              const ushort_t* __restrict__ W1p, const float* __restrict__ b1,
              const ushort_t* __restrict__ W2p, const float* __restrict__ b2,
              float* __restrict__ out){
  __shared__ ushort_t hbuf[64 * 384];
  char* h1b = (char*)hbuf;
  char* h2b = (char*)hbuf;
  const int tid  = threadIdx.x;
  const int lb   = ((blockIdx.x & 7) << 7) + (blockIdx.x >> 3);
  const int row0 = lb * 64;
  {
    const int r   = tid >> 2;
    const int sub = tid & 3;
    const int m   = row0 + r;
    const f32x4* xsr = (const f32x4*)(x_skip + (size_t)m * 128);
    f32x4 xs[8];
    #pragma unroll
    for (int it = 0; it < 8; ++it) xs[it] = xsr[it * 4 + sub];
    int i0 = knn_i[3*m], i1 = knn_i[3*m+1], i2 = knn_i[3*m+2];
    float w0 = knn_w[3*m], w1 = knn_w[3*m+1], w2 = knn_w[3*m+2];
    const f32x4* x0 = (const f32x4*)(x + (size_t)i0 * 256);
    const f32x4* x1 = (const f32x4*)(x + (size_t)i1 * 256);
    const f32x4* x2 = (const f32x4*)(x + (size_t)i2 * 256);
    #pragma unroll
    for (int it = 0; it < 16; ++it){
      int c4 = it * 4 + sub;
      f32x4 v = x0[c4] * w0 + x1[c4] * w1 + x2[c4] * w2;
      int byte = (r * 768 + c4 * 8) ^ ((r & 7) << 4);
      us4 pk = { f2bf(v.x), f2bf(v.y), f2bf(v.z), f2bf(v.w) };
      *(us4*)(h1b + byte) = pk;
    }
    #pragma unroll
    for (int it = 0; it < 8; ++it){
      int c4 = it * 4 + sub;
      f32x4 v = xs[it];
      int byte = (r * 768 + 512 + c4 * 8) ^ ((r & 7) << 4);
      us4 pk = { f2bf(v.x), f2bf(v.y), f2bf(v.z), f2bf(v.w) };
      *(us4*)(h1b + byte) = pk;
    }
  }
  __syncthreads();
  const int wp  = tid >> 6;
  const int lane = tid & 63;
  const int lhi = lane >> 4;
  const int llo = lane & 15;
  f32x4 acc[4][4];
  #pragma unroll
  for (int nbp = 0; nbp < 4; ++nbp){
    float bb = b1[wp * 64 + nbp * 16 + llo];
    #pragma unroll
    for (int mb = 0; mb < 4; ++mb) acc[mb][nbp] = splat4(bb);
  }
  #pragma unroll
  for (int kk = 0; kk < 12; ++kk){
    short8 af[4];
    #pragma unroll
    for (int mb = 0; mb < 4; ++mb){
      int r = mb * 16 + llo;
      int byte = (r * 768 + kk * 64 + lhi * 16) ^ ((r & 7) << 4);
      af[mb] = *(const short8*)(h1b + byte);
    }
    short8 bfr[4];
    #pragma unroll
    for (int nbp = 0; nbp < 4; ++nbp)
      bfr[nbp] = *(const short8*)(W1p + ((size_t)((kk * 16 + wp * 4 + nbp) * 64 + lane)) * 8);
    #pragma unroll
    for (int mb = 0; mb < 4; ++mb)
      #pragma unroll
      for (int nbp = 0; nbp < 4; ++nbp)
        acc[mb][nbp] = __builtin_amdgcn_mfma_f32_16x16x32_bf16(af[mb], bfr[nbp], acc[mb][nbp], 0, 0, 0);
  }
  __syncthreads();
  #pragma unroll
  for (int mb = 0; mb < 4; ++mb)
    #pragma unroll
    for (int nbp = 0; nbp < 4; ++nbp)
      #pragma unroll
      for (int rg = 0; rg < 4; ++rg){
        int r   = mb * 16 + lhi * 4 + rg;
        int col = wp * 64 + nbp * 16 + llo;
        int byte = (r * 512 + col * 2) ^ ((r & 7) << 4);
        *(ushort_t*)(h2b + byte) = f2bf(fmaxf(acc[mb][nbp][rg], 0.0f));
      }
  __syncthreads();
  f32x4 acc2[4][4];
  #pragma unroll
  for (int nbp = 0; nbp < 4; ++nbp){
    float bb = b2[wp * 64 + nbp * 16 + llo];
    #pragma unroll
    for (int mb = 0; mb < 4; ++mb) acc2[mb][nbp] = splat4(bb);
  }
  #pragma unroll
  for (int kk = 0; kk < 8; ++kk){
    short8 af[4];
    #pragma unroll
    for (int mb = 0; mb < 4; ++mb){
      int r = mb * 16 + llo;
      int byte = (r * 512 + kk * 64 + lhi * 16) ^ ((r & 7) << 4);
      af[mb] = *(const short8*)(h2b + byte);
    }
    short8 bfr[4];
    #pragma unroll
    for (int nbp = 0; nbp < 4; ++nbp)
      bfr[nbp] = *(const short8*)(W2p + ((size_t)((kk * 16 + wp * 4 + nbp) * 64 + lane)) * 8);
    #pragma unroll
    for (int mb = 0; mb < 4; ++mb)
      #pragma unroll
      for (int nbp = 0; nbp < 4; ++nbp)
        acc2[mb][nbp] = __builtin_amdgcn_mfma_f32_16x16x32_bf16(af[mb], bfr[nbp], acc2[mb][nbp], 0, 0, 0);
  }
  #pragma unroll
  for (int mb = 0; mb < 4; ++mb)
    #pragma unroll
    for (int nbp = 0; nbp < 4; ++nbp)
      #pragma unroll
      for (int rg = 0; rg < 4; ++rg){
        int row = row0 + mb * 16 + lhi * 4 + rg;
        int col = wp * 64 + nbp * 16 + llo;
        out[(size_t)row * 256 + col] = fmaxf(acc2[mb][nbp][rg], 0.0f);
      }
}

extern "C" void kernel_launch(void* const* d_in, const int* in_sizes, int n_in,
                              void* d_out, int out_size, void* d_ws, size_t ws_size,
                              hipStream_t stream){
  (void)in_sizes; (void)n_in; (void)out_size;
  const float* x        = (const float*)d_in[0];
  const float* pos      = (const float*)d_in[1];
  const float* x_skip   = (const float*)d_in[3];
  const float* pos_skip = (const float*)d_in[4];
  const float* W1 = (const float*)d_in[6];
  const float* b1 = (const float*)d_in[7];
  const float* W2 = (const float*)d_in[8];
  const float* b2 = (const float*)d_in[9];
  float* out = (float*)d_out;
  char* ws = (char*)d_ws;
  ushort_t* W1p = (ushort_t*)(ws);                    // 196608 B
  ushort_t* W2p = (ushort_t*)(ws + 196608);           // 131072 B
  int*      ki  = (int*)(ws + 327680);                // 786432 B
  float*    kw  = (float*)(ws + 1114112);             // 786432 B
  ushort_t* h1g = (ushort_t*)(ws + 1900544);          // 50331648 B
  const size_t WS_NEED = 1900544ull + 50331648ull;    // 52.2 MB

  hipLaunchKernelGGL(prep_w, dim3(384), dim3(256), 0, stream, W1, W1p, 98304);
  hipLaunchKernelGGL(prep_w, dim3(256), dim3(256), 0, stream, W2, W2p, 65536);
  hipLaunchKernelGGL(knn_kernel, dim3(2048), dim3(256), 0, stream, pos, pos_skip, ki, kw);
  if (ws_size >= WS_NEED){
    hipLaunchKernelGGL(stage_h1, dim3(2048), dim3(256), 0, stream,
                       x, x_skip, ki, kw, h1g);
    hipLaunchKernelGGL(gemm_fp, dim3(1024), dim3(256), 0, stream,
                       h1g, W1p, b1, W2p, b2, out);
  } else {
    hipLaunchKernelGGL(fused_fp, dim3(1024), dim3(256), 0, stream,
                       x, x_skip, ki, kw, W1p, b1, W2p, b2, out);
  }
}

// Round 6
// 89.717 us; speedup vs baseline: 1.2173x; 1.2173x over previous
//
#include <hip/hip_runtime.h>

typedef float  f32x4  __attribute__((ext_vector_type(4)));
typedef short  short8 __attribute__((ext_vector_type(8)));
typedef unsigned short ushort_t;
typedef ushort_t us4   __attribute__((ext_vector_type(4)));

#define NCOARSE 1024
#define NFINE   4096

__device__ __forceinline__ ushort_t f2bf(float f){
  union { float f; unsigned u; } a; a.f = f;
  unsigned u = a.u;
  return (ushort_t)((u + 0x7fffu + ((u >> 16) & 1u)) >> 16);
}

__device__ __forceinline__ f32x4 splat4(float v){ f32x4 t = {v, v, v, v}; return t; }

// ---- pack fp32 row-major W[K][256] into bf16, MFMA-B-fragment order:
// Wp[(((kc*16+nb)*64 + lane)*8 + j] = W[kc*32 + (lane>>4)*8 + j][nb*16 + (lane&15)]
__global__ void prep_w(const float* __restrict__ W, ushort_t* __restrict__ Wp, int nelem){
  int e = blockIdx.x * 256 + threadIdx.x;
  if (e >= nelem) return;
  int j    = e & 7;
  int lane = (e >> 3) & 63;
  int g    = e >> 9;        // kc*16 + nb
  int nb   = g & 15;
  int kc   = g >> 4;
  int k = kc * 32 + (lane >> 4) * 8 + j;
  int n = nb * 16 + (lane & 15);
  Wp[e] = f2bf(W[k * 256 + n]);
}

// ---- kNN, reference fp32 arithmetic EXACTLY (expansion form, no fma).
__global__ __launch_bounds__(256) void knn_kernel(const float* __restrict__ pos,
                           const float* __restrict__ pos_skip,
                           int* __restrict__ knn_i, float* __restrict__ knn_w){
  __shared__ f32x4 cand[8][129];
  const int tid = threadIdx.x;
  const int b   = blockIdx.x >> 7;
  const int m   = blockIdx.x * 32 + (tid >> 3);
  const int chunk = tid & 7;

  const float* p = pos + (size_t)b * NCOARSE * 3;
  for (int c = tid; c < NCOARSE; c += 256){
    float x = p[3*c], y = p[3*c+1], z = p[3*c+2];
    float sc = __fadd_rn(__fadd_rn(__fmul_rn(x,x), __fmul_rn(y,y)), __fmul_rn(z,z));
    f32x4 v = { x, y, z, sc };
    cand[c >> 7][c & 127] = v;
  }
  __syncthreads();

  const float* q = pos_skip + (size_t)m * 3;
  float qx = q[0], qy = q[1], qz = q[2];
  float sf = __fadd_rn(__fadd_rn(__fmul_rn(qx,qx), __fmul_rn(qy,qy)), __fmul_rn(qz,qz));

  float d0 = 1e30f, d1 = 1e30f, d2 = 1e30f;
  int   i0 = 0,     i1 = 0,     i2 = 0;
  const int gbase = chunk * 128;
  #pragma unroll 4
  for (int i = 0; i < 128; ++i){
    f32x4 v = cand[chunk][i];
    float dot = __fadd_rn(__fadd_rn(__fmul_rn(qx, v.x), __fmul_rn(qy, v.y)),
                          __fmul_rn(qz, v.z));
    float d = __fsub_rn(__fadd_rn(sf, v.w), __fmul_rn(2.0f, dot));
    d = fmaxf(d, 0.0f);
    if (d < d2){
      int gi = gbase + i;
      if (d < d1){
        d2 = d1; i2 = i1;
        if (d < d0){ d1 = d0; i1 = i0; d0 = d; i0 = gi; }
        else       { d1 = d;  i1 = gi; }
      } else { d2 = d; i2 = gi; }
    }
  }

  #pragma unroll
  for (int mlev = 1; mlev <= 4; mlev <<= 1){
    float e0 = __shfl_xor(d0, mlev), e1 = __shfl_xor(d1, mlev), e2 = __shfl_xor(d2, mlev);
    int   j0 = __shfl_xor(i0, mlev), j1 = __shfl_xor(i1, mlev), j2 = __shfl_xor(i2, mlev);
    #pragma unroll
    for (int s = 0; s < 3; ++s){
      float e = (s == 0) ? e0 : (s == 1) ? e1 : e2;
      int   j = (s == 0) ? j0 : (s == 1) ? j1 : j2;
      bool l2 = (e < d2) || (e == d2 && j < i2);
      if (l2){
        bool l1 = (e < d1) || (e == d1 && j < i1);
        if (l1){
          d2 = d1; i2 = i1;
          bool l0 = (e < d0) || (e == d0 && j < i0);
          if (l0){ d1 = d0; i1 = i0; d0 = e; i0 = j; }
          else   { d1 = e;  i1 = j; }
        } else { d2 = e; i2 = j; }
      }
    }
  }

  if (chunk == 0){
    float w0 = 1.0f / fmaxf(d0, 1e-16f);
    float w1 = 1.0f / fmaxf(d1, 1e-16f);
    float w2 = 1.0f / fmaxf(d2, 1e-16f);
    float ws = __fadd_rn(__fadd_rn(w0, w1), w2);
    knn_i[3*m]   = b * NCOARSE + i0;
    knn_i[3*m+1] = b * NCOARSE + i1;
    knn_i[3*m+2] = b * NCOARSE + i2;
    knn_w[3*m]   = w0 / ws;
    knn_w[3*m+1] = w1 / ws;
    knn_w[3*m+2] = w2 / ws;
  }
}

// W fragment load (from prepacked Wp): fragment f, lane slice
#define LDW(DST, WP, F)                                                     \
  { _Pragma("unroll")                                                       \
    for (int i_ = 0; i_ < 4; ++i_)                                          \
      DST[i_] = *(const short8*)((WP) + ((size_t)(((F) + i_) * 64 + lane)) * 8); }

// stage wst regs -> wbuf[BUF] (per-wave slots wp*4+i, 1KB each, linear lane*16)
#define STW(BUF, SRC)                                                       \
  { _Pragma("unroll")                                                       \
    for (int i_ = 0; i_ < 4; ++i_)                                          \
      *(short8*)&wbuf[BUF][(wp * 4 + i_) * 512 + lane * 8] = SRC[i_]; }

// one K-step of MFMAs: A from LDSBASE (stride STR, k-chunk KK), B from wbuf[BUF]
#define KSTEP(LDSBASE, STR, KK, BUF, ACC)                                   \
  { short8 af_[4], bf_[4];                                                  \
    _Pragma("unroll")                                                       \
    for (int mb_ = 0; mb_ < 4; ++mb_){                                      \
      int r_ = mb_ * 16 + llo;                                              \
      int byte_ = (r_ * (STR) + (KK) * 64 + lhi * 16) ^ ((r_ & 7) << 4);    \
      af_[mb_] = *(const short8*)((LDSBASE) + byte_);                       \
    }                                                                       \
    _Pragma("unroll")                                                       \
    for (int nb_ = 0; nb_ < 4; ++nb_)                                       \
      bf_[nb_] = *(const short8*)&wbuf[BUF][(wp * 4 + nb_) * 512 + lane * 8];\
    _Pragma("unroll")                                                       \
    for (int mb_ = 0; mb_ < 4; ++mb_)                                       \
      _Pragma("unroll")                                                     \
      for (int nb_ = 0; nb_ < 4; ++nb_)                                     \
        ACC[mb_][nb_] = __builtin_amdgcn_mfma_f32_16x16x32_bf16(            \
            af_[mb_], bf_[nb_], ACC[mb_][nb_], 0, 0, 0); }

// ---- fused: gather-stage -> GEMM1(relu) -> GEMM2(relu)
// W streams through 2x16KB LDS double-buffer with depth-1 register lookahead
// (m97 K-step shape: 4 stage + 8 ds_read + 16 MFMA + 1 barrier).
__global__ __launch_bounds__(256, 2)
void fused_fp(const float* __restrict__ x, const float* __restrict__ x_skip,
              const int* __restrict__ knn_i, const float* __restrict__ knn_w,
              const ushort_t* __restrict__ W1p, const float* __restrict__ b1,
              const ushort_t* __restrict__ W2p, const float* __restrict__ b2,
              float* __restrict__ out){
  __shared__ ushort_t hbuf[64 * 384];     // 48KB: h1, then h2 overlays
  __shared__ ushort_t wbuf[2][8192];      // 2 x 16KB W step buffers
  char* h1b = (char*)hbuf;
  char* h2b = (char*)hbuf;
  const int tid  = threadIdx.x;
  const int lb   = ((blockIdx.x & 7) << 7) + (blockIdx.x >> 3);  // bijective XCD swizzle
  const int row0 = lb * 64;
  const int wp   = tid >> 6;
  const int lane = tid & 63;
  const int lhi  = lane >> 4;
  const int llo  = lane & 15;

  short8 wst[4];
  LDW(wst, W1p, 0 * 16 + wp * 4);          // W1 step 0 -> regs (issued first)

  // ---- gather-stage h1 (4 threads/row; proven ~free inside this kernel)
  {
    const int r   = tid >> 2;
    const int sub = tid & 3;
    const int m   = row0 + r;
    const f32x4* xsr = (const f32x4*)(x_skip + (size_t)m * 128);
    f32x4 xs[8];
    #pragma unroll
    for (int it = 0; it < 8; ++it) xs[it] = xsr[it * 4 + sub];
    int i0 = knn_i[3*m], i1 = knn_i[3*m+1], i2 = knn_i[3*m+2];
    float w0 = knn_w[3*m], w1 = knn_w[3*m+1], w2 = knn_w[3*m+2];
    const f32x4* x0 = (const f32x4*)(x + (size_t)i0 * 256);
    const f32x4* x1 = (const f32x4*)(x + (size_t)i1 * 256);
    const f32x4* x2 = (const f32x4*)(x + (size_t)i2 * 256);
    #pragma unroll
    for (int it = 0; it < 16; ++it){
      int c4 = it * 4 + sub;
      f32x4 v = x0[c4] * w0 + x1[c4] * w1 + x2[c4] * w2;
      int byte = (r * 768 + c4 * 8) ^ ((r & 7) << 4);
      us4 pk = { f2bf(v.x), f2bf(v.y), f2bf(v.z), f2bf(v.w) };
      *(us4*)(h1b + byte) = pk;
    }
    #pragma unroll
    for (int it = 0; it < 8; ++it){
      int c4 = it * 4 + sub;
      f32x4 v = xs[it];
      int byte = (r * 768 + 512 + c4 * 8) ^ ((r & 7) << 4);
      us4 pk = { f2bf(v.x), f2bf(v.y), f2bf(v.z), f2bf(v.w) };
      *(us4*)(h1b + byte) = pk;
    }
  }
  STW(0, wst);                              // W1 step 0 -> wbuf[0]
  LDW(wst, W1p, 1 * 16 + wp * 4);           // W1 step 1 -> regs
  __syncthreads();                          // h1 + wbuf[0] ready

  // ---- GEMM1: 12 K-steps; invariant: entering step kk, wst holds step kk+1
  f32x4 acc[4][4];
  #pragma unroll
  for (int nbp = 0; nbp < 4; ++nbp){
    float bb = b1[wp * 64 + nbp * 16 + llo];
    #pragma unroll
    for (int mb = 0; mb < 4; ++mb) acc[mb][nbp] = splat4(bb);
  }
  #pragma unroll
  for (int kk = 0; kk < 12; ++kk){
    STW((kk + 1) & 1, wst);                 // stage step kk+1
    if (kk < 10)      { LDW(wst, W1p, (kk + 2) * 16 + wp * 4); }
    else if (kk == 10){ LDW(wst, W2p, 0 * 16 + wp * 4); }       // W2 step 0
    else              { LDW(wst, W2p, 1 * 16 + wp * 4); }       // W2 step 1
    KSTEP(h1b, 768, kk, kk & 1, acc);
    __syncthreads();
  }
  // wbuf[0] = W2 step 0; wst = W2 step 1; h1 reads all done.

  // ---- relu -> bf16 -> h2 (overlays h1)
  #pragma unroll
  for (int mb = 0; mb < 4; ++mb)
    #pragma unroll
    for (int nbp = 0; nbp < 4; ++nbp)
      #pragma unroll
      for (int rg = 0; rg < 4; ++rg){
        int r   = mb * 16 + lhi * 4 + rg;
        int col = wp * 64 + nbp * 16 + llo;
        int byte = (r * 512 + col * 2) ^ ((r & 7) << 4);
        *(ushort_t*)(h2b + byte) = f2bf(fmaxf(acc[mb][nbp][rg], 0.0f));
      }
  __syncthreads();                          // h2 ready; wbuf[0] ready

  // ---- GEMM2: 8 K-steps; entering step t, wst holds step t+1
  f32x4 acc2[4][4];
  #pragma unroll
  for (int nbp = 0; nbp < 4; ++nbp){
    float bb = b2[wp * 64 + nbp * 16 + llo];
    #pragma unroll
    for (int mb = 0; mb < 4; ++mb) acc2[mb][nbp] = splat4(bb);
  }
  #pragma unroll
  for (int t = 0; t < 8; ++t){
    if (t < 7) STW((t + 1) & 1, wst);       // stage step t+1
    if (t < 6) { LDW(wst, W2p, (t + 2) * 16 + wp * 4); }
    KSTEP(h2b, 512, t, t & 1, acc2);
    if (t < 7) __syncthreads();
  }

  // ---- relu -> fp32 out
  #pragma unroll
  for (int mb = 0; mb < 4; ++mb)
    #pragma unroll
    for (int nbp = 0; nbp < 4; ++nbp)
      #pragma unroll
      for (int rg = 0; rg < 4; ++rg){
        int row = row0 + mb * 16 + lhi * 4 + rg;
        int col = wp * 64 + nbp * 16 + llo;
        out[(size_t)row * 256 + col] = fmaxf(acc2[mb][nbp][rg], 0.0f);
      }
}

extern "C" void kernel_launch(void* const* d_in, const int* in_sizes, int n_in,
                              void* d_out, int out_size, void* d_ws, size_t ws_size,
                              hipStream_t stream){
  (void)in_sizes; (void)n_in; (void)out_size; (void)ws_size;
  const float* x        = (const float*)d_in[0];
  const float* pos      = (const float*)d_in[1];
  const float* x_skip   = (const float*)d_in[3];
  const float* pos_skip = (const float*)d_in[4];
  const float* W1 = (const float*)d_in[6];
  const float* b1 = (const float*)d_in[7];
  const float* W2 = (const float*)d_in[8];
  const float* b2 = (const float*)d_in[9];
  float* out = (float*)d_out;
  char* ws = (char*)d_ws;
  ushort_t* W1p = (ushort_t*)(ws);                 // 196608 B
  ushort_t* W2p = (ushort_t*)(ws + 196608);        // 131072 B
  int*      ki  = (int*)(ws + 327680);             // 786432 B
  float*    kw  = (float*)(ws + 1114112);          // 786432 B

  hipLaunchKernelGGL(prep_w, dim3(384), dim3(256), 0, stream, W1, W1p, 98304);
  hipLaunchKernelGGL(prep_w, dim3(256), dim3(256), 0, stream, W2, W2p, 65536);
  hipLaunchKernelGGL(knn_kernel, dim3(2048), dim3(256), 0, stream, pos, pos_skip, ki, kw);
  hipLaunchKernelGGL(fused_fp, dim3(1024), dim3(256), 0, stream,
                     x, x_skip, ki, kw, W1p, b1, W2p, b2, out);
}

// Round 7
// 87.907 us; speedup vs baseline: 1.2424x; 1.0206x over previous
//
#include <hip/hip_runtime.h>

typedef float  f32x4  __attribute__((ext_vector_type(4)));
typedef short  short8 __attribute__((ext_vector_type(8)));
typedef unsigned short ushort_t;
typedef ushort_t us4   __attribute__((ext_vector_type(4)));

#define NCOARSE 1024
#define NFINE   4096

__device__ __forceinline__ ushort_t f2bf(float f){
  union { float f; unsigned u; } a; a.f = f;
  unsigned u = a.u;
  return (ushort_t)((u + 0x7fffu + ((u >> 16) & 1u)) >> 16);
}

__device__ __forceinline__ f32x4 splat4(float v){ f32x4 t = {v, v, v, v}; return t; }

// ---- pack fp32 row-major W[K][256] into bf16, MFMA-B-fragment order:
// Wp[(((kc*16+nb)*64 + lane)*8 + j] = W[kc*32 + (lane>>4)*8 + j][nb*16 + (lane&15)]
__global__ void prep_w(const float* __restrict__ W, ushort_t* __restrict__ Wp, int nelem){
  int e = blockIdx.x * 256 + threadIdx.x;
  if (e >= nelem) return;
  int j    = e & 7;
  int lane = (e >> 3) & 63;
  int g    = e >> 9;        // kc*16 + nb
  int nb   = g & 15;
  int kc   = g >> 4;
  int k = kc * 32 + (lane >> 4) * 8 + j;
  int n = nb * 16 + (lane & 15);
  Wp[e] = f2bf(W[k * 256 + n]);
}

// ---- kNN, reference fp32 arithmetic EXACTLY (expansion form, no fma).
__global__ __launch_bounds__(256) void knn_kernel(const float* __restrict__ pos,
                           const float* __restrict__ pos_skip,
                           int* __restrict__ knn_i, float* __restrict__ knn_w){
  __shared__ f32x4 cand[8][129];
  const int tid = threadIdx.x;
  const int b   = blockIdx.x >> 7;
  const int m   = blockIdx.x * 32 + (tid >> 3);
  const int chunk = tid & 7;

  const float* p = pos + (size_t)b * NCOARSE * 3;
  for (int c = tid; c < NCOARSE; c += 256){
    float x = p[3*c], y = p[3*c+1], z = p[3*c+2];
    float sc = __fadd_rn(__fadd_rn(__fmul_rn(x,x), __fmul_rn(y,y)), __fmul_rn(z,z));
    f32x4 v = { x, y, z, sc };
    cand[c >> 7][c & 127] = v;
  }
  __syncthreads();

  const float* q = pos_skip + (size_t)m * 3;
  float qx = q[0], qy = q[1], qz = q[2];
  float sf = __fadd_rn(__fadd_rn(__fmul_rn(qx,qx), __fmul_rn(qy,qy)), __fmul_rn(qz,qz));

  float d0 = 1e30f, d1 = 1e30f, d2 = 1e30f;
  int   i0 = 0,     i1 = 0,     i2 = 0;
  const int gbase = chunk * 128;
  #pragma unroll 4
  for (int i = 0; i < 128; ++i){
    f32x4 v = cand[chunk][i];
    float dot = __fadd_rn(__fadd_rn(__fmul_rn(qx, v.x), __fmul_rn(qy, v.y)),
                          __fmul_rn(qz, v.z));
    float d = __fsub_rn(__fadd_rn(sf, v.w), __fmul_rn(2.0f, dot));
    d = fmaxf(d, 0.0f);
    if (d < d2){
      int gi = gbase + i;
      if (d < d1){
        d2 = d1; i2 = i1;
        if (d < d0){ d1 = d0; i1 = i0; d0 = d; i0 = gi; }
        else       { d1 = d;  i1 = gi; }
      } else { d2 = d; i2 = gi; }
    }
  }

  #pragma unroll
  for (int mlev = 1; mlev <= 4; mlev <<= 1){
    float e0 = __shfl_xor(d0, mlev), e1 = __shfl_xor(d1, mlev), e2 = __shfl_xor(d2, mlev);
    int   j0 = __shfl_xor(i0, mlev), j1 = __shfl_xor(i1, mlev), j2 = __shfl_xor(i2, mlev);
    #pragma unroll
    for (int s = 0; s < 3; ++s){
      float e = (s == 0) ? e0 : (s == 1) ? e1 : e2;
      int   j = (s == 0) ? j0 : (s == 1) ? j1 : j2;
      bool l2 = (e < d2) || (e == d2 && j < i2);
      if (l2){
        bool l1 = (e < d1) || (e == d1 && j < i1);
        if (l1){
          d2 = d1; i2 = i1;
          bool l0 = (e < d0) || (e == d0 && j < i0);
          if (l0){ d1 = d0; i1 = i0; d0 = e; i0 = j; }
          else   { d1 = e;  i1 = j; }
        } else { d2 = e; i2 = j; }
      }
    }
  }

  if (chunk == 0){
    float w0 = 1.0f / fmaxf(d0, 1e-16f);
    float w1 = 1.0f / fmaxf(d1, 1e-16f);
    float w2 = 1.0f / fmaxf(d2, 1e-16f);
    float ws = __fadd_rn(__fadd_rn(w0, w1), w2);
    knn_i[3*m]   = b * NCOARSE + i0;
    knn_i[3*m+1] = b * NCOARSE + i1;
    knn_i[3*m+2] = b * NCOARSE + i2;
    knn_w[3*m]   = w0 / ws;
    knn_w[3*m+1] = w1 / ws;
    knn_w[3*m+2] = w2 / ws;
  }
}

// ---- fused: gather-stage -> GEMM1(relu) -> GEMM2(relu)
// 32-row tile, 24KB LDS -> ~5-6 blocks/CU (latency hidden by block TLP).
// W direct from global (L2-resident), barrier-free K-loops, 3 barriers total.
__global__ __launch_bounds__(256, 4)
void fused_fp(const float* __restrict__ x, const float* __restrict__ x_skip,
              const int* __restrict__ knn_i, const float* __restrict__ knn_w,
              const ushort_t* __restrict__ W1p, const float* __restrict__ b1,
              const ushort_t* __restrict__ W2p, const float* __restrict__ b2,
              float* __restrict__ out){
  __shared__ ushort_t hbuf[32 * 384];     // 24KB: h1 (swizzled), h2 overlays
  char* h1b = (char*)hbuf;
  char* h2b = (char*)hbuf;
  const int tid  = threadIdx.x;
  const int lb   = ((blockIdx.x & 7) << 8) + (blockIdx.x >> 3);  // bijective: 2048 = 8*256
  const int row0 = lb * 32;
  const int wp   = tid >> 6;
  const int lane = tid & 63;
  const int lhi  = lane >> 4;
  const int llo  = lane & 15;

  // ---- gather-stage h1: 8 threads per row
  {
    const int r   = tid >> 3;
    const int sub = tid & 7;
    const int m   = row0 + r;
    const f32x4* xsr = (const f32x4*)(x_skip + (size_t)m * 128);
    f32x4 xs[4];
    #pragma unroll
    for (int it = 0; it < 4; ++it) xs[it] = xsr[it * 8 + sub];
    int i0 = knn_i[3*m], i1 = knn_i[3*m+1], i2 = knn_i[3*m+2];
    float w0 = knn_w[3*m], w1 = knn_w[3*m+1], w2 = knn_w[3*m+2];
    const f32x4* x0 = (const f32x4*)(x + (size_t)i0 * 256);
    const f32x4* x1 = (const f32x4*)(x + (size_t)i1 * 256);
    const f32x4* x2 = (const f32x4*)(x + (size_t)i2 * 256);
    #pragma unroll
    for (int it = 0; it < 8; ++it){
      int c4 = it * 8 + sub;
      f32x4 v = x0[c4] * w0 + x1[c4] * w1 + x2[c4] * w2;
      int byte = (r * 768 + c4 * 8) ^ ((r & 7) << 4);
      us4 pk = { f2bf(v.x), f2bf(v.y), f2bf(v.z), f2bf(v.w) };
      *(us4*)(h1b + byte) = pk;
    }
    #pragma unroll
    for (int it = 0; it < 4; ++it){
      int c4 = it * 8 + sub;
      f32x4 v = xs[it];
      int byte = (r * 768 + 512 + c4 * 8) ^ ((r & 7) << 4);
      us4 pk = { f2bf(v.x), f2bf(v.y), f2bf(v.z), f2bf(v.w) };
      *(us4*)(h1b + byte) = pk;
    }
  }
  __syncthreads();

  // ---- GEMM1: (32x384) @ (384x256), no barriers in K-loop
  f32x4 acc[2][4];
  #pragma unroll
  for (int nbp = 0; nbp < 4; ++nbp){
    float bb = b1[wp * 64 + nbp * 16 + llo];
    #pragma unroll
    for (int mb = 0; mb < 2; ++mb) acc[mb][nbp] = splat4(bb);
  }
  #pragma unroll
  for (int kk = 0; kk < 12; ++kk){
    short8 af[2];
    #pragma unroll
    for (int mb = 0; mb < 2; ++mb){
      int r = mb * 16 + llo;
      int byte = (r * 768 + kk * 64 + lhi * 16) ^ ((r & 7) << 4);
      af[mb] = *(const short8*)(h1b + byte);
    }
    short8 bfr[4];
    #pragma unroll
    for (int nbp = 0; nbp < 4; ++nbp)
      bfr[nbp] = *(const short8*)(W1p + ((size_t)((kk * 16 + wp * 4 + nbp) * 64 + lane)) * 8);
    #pragma unroll
    for (int mb = 0; mb < 2; ++mb)
      #pragma unroll
      for (int nbp = 0; nbp < 4; ++nbp)
        acc[mb][nbp] = __builtin_amdgcn_mfma_f32_16x16x32_bf16(af[mb], bfr[nbp], acc[mb][nbp], 0, 0, 0);
  }
  __syncthreads();   // all h1 reads done before h2 overlays the buffer

  // ---- relu -> bf16 -> h2 (swizzled, overlays h1)
  #pragma unroll
  for (int mb = 0; mb < 2; ++mb)
    #pragma unroll
    for (int nbp = 0; nbp < 4; ++nbp)
      #pragma unroll
      for (int rg = 0; rg < 4; ++rg){
        int r   = mb * 16 + lhi * 4 + rg;
        int col = wp * 64 + nbp * 16 + llo;
        int byte = (r * 512 + col * 2) ^ ((r & 7) << 4);
        *(ushort_t*)(h2b + byte) = f2bf(fmaxf(acc[mb][nbp][rg], 0.0f));
      }
  __syncthreads();

  // ---- GEMM2: (32x256) @ (256x256)
  f32x4 acc2[2][4];
  #pragma unroll
  for (int nbp = 0; nbp < 4; ++nbp){
    float bb = b2[wp * 64 + nbp * 16 + llo];
    #pragma unroll
    for (int mb = 0; mb < 2; ++mb) acc2[mb][nbp] = splat4(bb);
  }
  #pragma unroll
  for (int kk = 0; kk < 8; ++kk){
    short8 af[2];
    #pragma unroll
    for (int mb = 0; mb < 2; ++mb){
      int r = mb * 16 + llo;
      int byte = (r * 512 + kk * 64 + lhi * 16) ^ ((r & 7) << 4);
      af[mb] = *(const short8*)(h2b + byte);
    }
    short8 bfr[4];
    #pragma unroll
    for (int nbp = 0; nbp < 4; ++nbp)
      bfr[nbp] = *(const short8*)(W2p + ((size_t)((kk * 16 + wp * 4 + nbp) * 64 + lane)) * 8);
    #pragma unroll
    for (int mb = 0; mb < 2; ++mb)
      #pragma unroll
      for (int nbp = 0; nbp < 4; ++nbp)
        acc2[mb][nbp] = __builtin_amdgcn_mfma_f32_16x16x32_bf16(af[mb], bfr[nbp], acc2[mb][nbp], 0, 0, 0);
  }

  // ---- relu -> fp32 out
  #pragma unroll
  for (int mb = 0; mb < 2; ++mb)
    #pragma unroll
    for (int nbp = 0; nbp < 4; ++nbp)
      #pragma unroll
      for (int rg = 0; rg < 4; ++rg){
        int row = row0 + mb * 16 + lhi * 4 + rg;
        int col = wp * 64 + nbp * 16 + llo;
        out[(size_t)row * 256 + col] = fmaxf(acc2[mb][nbp][rg], 0.0f);
      }
}

extern "C" void kernel_launch(void* const* d_in, const int* in_sizes, int n_in,
                              void* d_out, int out_size, void* d_ws, size_t ws_size,
                              hipStream_t stream){
  (void)in_sizes; (void)n_in; (void)out_size; (void)ws_size;
  const float* x        = (const float*)d_in[0];
  const float* pos      = (const float*)d_in[1];
  const float* x_skip   = (const float*)d_in[3];
  const float* pos_skip = (const float*)d_in[4];
  const float* W1 = (const float*)d_in[6];
  const float* b1 = (const float*)d_in[7];
  const float* W2 = (const float*)d_in[8];
  const float* b2 = (const float*)d_in[9];
  float* out = (float*)d_out;
  char* ws = (char*)d_ws;
  ushort_t* W1p = (ushort_t*)(ws);                 // 196608 B
  ushort_t* W2p = (ushort_t*)(ws + 196608);        // 131072 B
  int*      ki  = (int*)(ws + 327680);             // 786432 B
  float*    kw  = (float*)(ws + 1114112);          // 786432 B

  hipLaunchKernelGGL(prep_w, dim3(384), dim3(256), 0, stream, W1, W1p, 98304);
  hipLaunchKernelGGL(prep_w, dim3(256), dim3(256), 0, stream, W2, W2p, 65536);
  hipLaunchKernelGGL(knn_kernel, dim3(2048), dim3(256), 0, stream, pos, pos_skip, ki, kw);
  hipLaunchKernelGGL(fused_fp, dim3(2048), dim3(256), 0, stream,
                     x, x_skip, ki, kw, W1p, b1, W2p, b2, out);
}